// Round 4
// baseline (138.718 us; speedup 1.0000x reference)
//
#include <hip/hip_runtime.h>

#define NB 16          // batch
#define NH 512
#define NW 512

typedef float f32x4 __attribute__((ext_vector_type(4)));

// db2 decomposition filters
__device__ __constant__ float DLO[4] = {-0.12940952255092145f, 0.22414386804185735f, 0.836516303737469f, 0.48296291314469025f};
__device__ __constant__ float DHI[4] = {-0.48296291314469025f, 0.836516303737469f, -0.22414386804185735f, -0.12940952255092145f};

__device__ inline float wave_max(float v) {
    #pragma unroll
    for (int off = 32; off; off >>= 1) v = fmaxf(v, __shfl_xor(v, off, 64));
    return v;
}

// Level-1 DWT: x (512x512) -> a1 (256x256, scratch), (ad1,da1,dd1)*hfw into arr quadrants.
__global__ __launch_bounds__(256) void k_dwt1(const float* __restrict__ x,
                                              const float* __restrict__ hfw,
                                              float* __restrict__ arr_hf,
                                              float* __restrict__ a1,
                                              unsigned int* __restrict__ maxbuf) {
    int b = blockIdx.y;
    int idx = blockIdx.x * 256 + threadIdx.x;
    int r = idx >> 8, c = idx & 255;
    const float* xb = x + (size_t)b * (NH * NW);

    float X[4][4];
    if (r >= 1 && c >= 1) {
        const float* p = xb + (2 * r - 2) * 512 + (2 * c - 2);
        #pragma unroll
        for (int k = 0; k < 4; ++k) {
            float2 u0 = *(const float2*)(p + k * 512);
            float2 u1 = *(const float2*)(p + k * 512 + 2);
            X[k][0] = u0.x; X[k][1] = u0.y; X[k][2] = u1.x; X[k][3] = u1.y;
        }
    } else {
        #pragma unroll
        for (int k = 0; k < 4; ++k) {
            int rr = (2 * r - 2 + k + 512) & 511;
            #pragma unroll
            for (int l = 0; l < 4; ++l) {
                int cc = (2 * c - 2 + l + 512) & 511;
                X[k][l] = xb[rr * 512 + cc];
            }
        }
    }
    // lo[l] here equals original lo[3-l]; second stage uses reversed taps so results match.
    float lo[4], hi[4];
    #pragma unroll
    for (int l = 0; l < 4; ++l) {
        float alo = 0.f, ahi = 0.f;
        #pragma unroll
        for (int k = 0; k < 4; ++k) { alo += DLO[3 - k] * X[k][l]; ahi += DHI[3 - k] * X[k][l]; }
        lo[l] = alo; hi[l] = ahi;
    }
    float va = 0.f, vad = 0.f, vda = 0.f, vdd = 0.f;
    #pragma unroll
    for (int l = 0; l < 4; ++l) {
        va  += DLO[3 - l] * lo[l];
        vad += DHI[3 - l] * lo[l];
        vda += DLO[3 - l] * hi[l];
        vdd += DHI[3 - l] * hi[l];
    }

    a1[b * 65536 + r * 256 + c] = va;
    float* arr = arr_hf + (size_t)b * (512 * 512);
    int p_tr = r * 512 + (c + 256);
    int p_bl = (r + 256) * 512 + c;
    int p_br = (r + 256) * 512 + (c + 256);
    arr[p_tr] = vad * hfw[p_tr];
    arr[p_bl] = vda * hfw[p_bl];
    arr[p_br] = vdd * hfw[p_br];

    __shared__ float wmax[4][3];
    int wv = threadIdx.x >> 6, ln = threadIdx.x & 63;
    float m0 = wave_max(fabsf(vad));
    float m1 = wave_max(fabsf(vda));
    float m2 = wave_max(fabsf(vdd));
    if (ln == 0) { wmax[wv][0] = m0; wmax[wv][1] = m1; wmax[wv][2] = m2; }
    __syncthreads();
    if (threadIdx.x < 3) {
        int i = threadIdx.x;
        float m = fmaxf(fmaxf(wmax[0][i], wmax[1][i]), fmaxf(wmax[2][i], wmax[3][i]));
        atomicMax(maxbuf + b * 8 + i, __float_as_uint(m));
    }
}

// Level-2 DWT: a1 -> (a2,ad2,da2,dd2)*hfw into arr top-left 256x256; g2 = a2*lfw scratch.
__global__ __launch_bounds__(256) void k_dwt2(const float* __restrict__ a1,
                                              const float* __restrict__ hfw,
                                              const float* __restrict__ lfw,
                                              float* __restrict__ arr_hf,
                                              float* __restrict__ g2,
                                              unsigned int* __restrict__ maxbuf) {
    int b = blockIdx.y;
    int idx = blockIdx.x * 256 + threadIdx.x;
    int r = idx >> 7, c = idx & 127;
    const float* ab = a1 + b * 65536;

    float X[4][4];
    if (r >= 1 && c >= 1) {
        const float* p = ab + (2 * r - 2) * 256 + (2 * c - 2);
        #pragma unroll
        for (int k = 0; k < 4; ++k) {
            float2 u0 = *(const float2*)(p + k * 256);
            float2 u1 = *(const float2*)(p + k * 256 + 2);
            X[k][0] = u0.x; X[k][1] = u0.y; X[k][2] = u1.x; X[k][3] = u1.y;
        }
    } else {
        #pragma unroll
        for (int k = 0; k < 4; ++k) {
            int rr = (2 * r - 2 + k + 256) & 255;
            #pragma unroll
            for (int l = 0; l < 4; ++l) {
                int cc = (2 * c - 2 + l + 256) & 255;
                X[k][l] = ab[rr * 256 + cc];
            }
        }
    }
    float lo[4], hi[4];
    #pragma unroll
    for (int l = 0; l < 4; ++l) {
        float alo = 0.f, ahi = 0.f;
        #pragma unroll
        for (int k = 0; k < 4; ++k) { alo += DLO[3 - k] * X[k][l]; ahi += DHI[3 - k] * X[k][l]; }
        lo[l] = alo; hi[l] = ahi;
    }
    float va = 0.f, vad = 0.f, vda = 0.f, vdd = 0.f;
    #pragma unroll
    for (int l = 0; l < 4; ++l) {
        va  += DLO[3 - l] * lo[l];
        vad += DHI[3 - l] * lo[l];
        vda += DLO[3 - l] * hi[l];
        vdd += DHI[3 - l] * hi[l];
    }

    g2[b * 16384 + r * 128 + c] = va * lfw[r * 128 + c];
    float* arr = arr_hf + (size_t)b * (512 * 512);
    int p_tl = r * 512 + c;
    int p_tr = r * 512 + (c + 128);
    int p_bl = (r + 128) * 512 + c;
    int p_br = (r + 128) * 512 + (c + 128);
    arr[p_tl] = va  * hfw[p_tl];
    arr[p_tr] = vad * hfw[p_tr];
    arr[p_bl] = vda * hfw[p_bl];
    arr[p_br] = vdd * hfw[p_br];

    __shared__ float wmax[4][4];
    int wv = threadIdx.x >> 6, ln = threadIdx.x & 63;
    float m0 = wave_max(fabsf(va));
    float m1 = wave_max(fabsf(vad));
    float m2 = wave_max(fabsf(vda));
    float m3 = wave_max(fabsf(vdd));
    if (ln == 0) { wmax[wv][0] = m0; wmax[wv][1] = m1; wmax[wv][2] = m2; wmax[wv][3] = m3; }
    __syncthreads();
    if (threadIdx.x < 4) {
        int i = threadIdx.x;
        float m = fmaxf(fmaxf(wmax[0][i], wmax[1][i]), fmaxf(wmax[2][i], wmax[3][i]));
        atomicMax(maxbuf + b * 8 + 3 + i, __float_as_uint(m));
    }
}

// Fused: normalize (ch0 from arr_hf), bilinear of g2*inv_a2 (ch1), 3x3 conv 2->16, +bias.
// Tile 128w x 8h per 256-thread block. tid>>6 picks 4 oc (weights in regs). Each lane:
// w-quad wq=lane&31, row parity rp=lane>>5, output rows rp+{0,2,4,6} -> 16 px, 4 oc.
__global__ __launch_bounds__(256) void k_conv(const float* __restrict__ arr_hf,
                                              const float* __restrict__ g2,
                                              const unsigned int* __restrict__ maxbuf,
                                              const float* __restrict__ cw,
                                              const float* __restrict__ cb,
                                              float* __restrict__ out) {
    int b   = blockIdx.z;
    int th0 = blockIdx.y * 8;
    int tw0 = blockIdx.x * 128;
    int tid = threadIdx.x;
    int ocg  = tid >> 6;
    int lane = tid & 63;

    __shared__ __align__(16) float tile[2][10][132];

    // per-thread weights: oc in [ocg*4, ocg*4+4), layout cw[oc][ic][kh][kw]
    float wreg[72], breg[4];
    {
        const float4* wp = (const float4*)(cw + ocg * 72);   // 288B-aligned
        #pragma unroll
        for (int i = 0; i < 18; ++i) {
            float4 t = wp[i];
            wreg[4 * i] = t.x; wreg[4 * i + 1] = t.y; wreg[4 * i + 2] = t.z; wreg[4 * i + 3] = t.w;
        }
        #pragma unroll
        for (int o = 0; o < 4; ++o) breg[o] = cb[ocg * 4 + o];
    }

    const unsigned int* mb = maxbuf + b * 8;
    float inv_ad1 = 1.f / __uint_as_float(mb[0]);
    float inv_da1 = 1.f / __uint_as_float(mb[1]);
    float inv_dd1 = 1.f / __uint_as_float(mb[2]);
    float inv_a2  = 1.f / __uint_as_float(mb[3]);
    float inv_ad2 = 1.f / __uint_as_float(mb[4]);
    float inv_da2 = 1.f / __uint_as_float(mb[5]);
    float inv_dd2 = 1.f / __uint_as_float(mb[6]);

    const float* arr = arr_hf + (size_t)b * (512 * 512);
    const float* g2b = g2 + b * 16384;

    for (int i = tid; i < 10 * 130; i += 256) {
        int row = i / 130;
        int col = i - row * 130;
        int gh = th0 + row - 1;
        int gw = tw0 + col - 1;
        float v0 = 0.f, v1 = 0.f;
        if (gh >= 0 && gh < 512 && gw >= 0 && gw < 512) {
            // channel 0: (quad-tree * hfw) * inv(quadrant)
            float inv;
            if (gh < 256) {
                if (gw < 256) {
                    if (gh < 128) inv = (gw < 128) ? inv_a2 : inv_ad2;
                    else          inv = (gw < 128) ? inv_da2 : inv_dd2;
                } else inv = inv_ad1;
            } else inv = (gw < 256) ? inv_da1 : inv_dd1;
            v0 = arr[gh * 512 + gw] * inv;

            // channel 1: bilinear of (a2*lfw) then * inv_a2
            float sh = fminf(fmaxf(0.25f * (float)gh - 0.375f, 0.f), 127.f);
            float sw = fminf(fmaxf(0.25f * (float)gw - 0.375f, 0.f), 127.f);
            int r0 = (int)sh; float fr = sh - (float)r0; int r1 = min(r0 + 1, 127);
            int c0 = (int)sw; float fc = sw - (float)c0; int c1 = min(c0 + 1, 127);
            float g00 = g2b[r0 * 128 + c0];
            float g01 = g2b[r0 * 128 + c1];
            float g10 = g2b[r1 * 128 + c0];
            float g11 = g2b[r1 * 128 + c1];
            float t0 = g00 * (1.f - fr) + g10 * fr;
            float t1 = g01 * (1.f - fr) + g11 * fr;
            v1 = (t0 * (1.f - fc) + t1 * fc) * inv_a2;
        }
        tile[0][row][col] = v0;
        tile[1][row][col] = v1;
    }
    __syncthreads();

    int wq = lane & 31;   // w-quad: w0 = 4*wq
    int rp = lane >> 5;   // output rows rp, rp+2, rp+4, rp+6

    float acc[4][4][4];   // [ro][oc][j]
    #pragma unroll
    for (int ro = 0; ro < 4; ++ro)
        #pragma unroll
        for (int o = 0; o < 4; ++o)
            #pragma unroll
            for (int j = 0; j < 4; ++j) acc[ro][o][j] = breg[o];

#define FMA_PAIR(KH, RO)                                                          \
    {                                                                             \
        _Pragma("unroll")                                                         \
        for (int kw = 0; kw < 3; ++kw) {                                          \
            _Pragma("unroll")                                                     \
            for (int o = 0; o < 4; ++o) {                                         \
                float wv = wreg[o * 18 + ic * 9 + (KH) * 3 + kw];                 \
                _Pragma("unroll")                                                 \
                for (int j = 0; j < 4; ++j)                                       \
                    acc[RO][o][j] = fmaf(v[j + kw], wv, acc[RO][o][j]);           \
            }                                                                     \
        }                                                                         \
    }

    #pragma unroll
    for (int ic = 0; ic < 2; ++ic) {
        #pragma unroll
        for (int rr = 0; rr < 9; ++rr) {
            const float* rowp = &tile[ic][rp + rr][4 * wq];
            float v[6];
            { float4 t = *(const float4*)rowp; v[0] = t.x; v[1] = t.y; v[2] = t.z; v[3] = t.w;
              float2 s = *(const float2*)(rowp + 4); v[4] = s.x; v[5] = s.y; }
            if (rr % 2 == 0) {
                if (rr / 2 <= 3) FMA_PAIR(0, rr / 2);
                if (rr >= 2)     FMA_PAIR(2, (rr - 2) / 2);
            } else {
                FMA_PAIR(1, (rr - 1) / 2);
            }
        }
    }
#undef FMA_PAIR

    size_t plane = 512 * 512;
    float* ob = out + (size_t)(b * 16 + ocg * 4) * plane + (size_t)th0 * 512 + tw0 + 4 * wq;
    #pragma unroll
    for (int o = 0; o < 4; ++o) {
        #pragma unroll
        for (int ro = 0; ro < 4; ++ro) {
            int row = rp + 2 * ro;
            f32x4 val = { acc[ro][o][0], acc[ro][o][1], acc[ro][o][2], acc[ro][o][3] };
            __builtin_nontemporal_store(val, (f32x4*)(ob + (size_t)o * plane + (size_t)row * 512));
        }
    }
}

extern "C" void kernel_launch(void* const* d_in, const int* in_sizes, int n_in,
                              void* d_out, int out_size, void* d_ws, size_t ws_size,
                              hipStream_t stream) {
    const float* x   = (const float*)d_in[0];
    const float* hfw = (const float*)d_in[1];
    const float* lfw = (const float*)d_in[2];
    const float* cw  = (const float*)d_in[3];
    const float* cb  = (const float*)d_in[4];
    float* out = (float*)d_out;

    char* ws = (char*)d_ws;
    float* arr_hf       = (float*)(ws);                    // 16 MiB: 16 x 512 x 512 (pre-multiplied by hfw)
    float* a1           = (float*)(ws + 16777216);         //  4 MiB: 16 x 256 x 256
    float* g2           = (float*)(ws + 20971520);         //  1 MiB: 16 x 128 x 128 (a2 * lfw)
    unsigned int* maxbf = (unsigned int*)(ws + 22020096);  //  16 x 8 u32

    (void)hipMemsetAsync(maxbf, 0, NB * 8 * sizeof(unsigned int), stream);
    k_dwt1<<<dim3(256, NB), 256, 0, stream>>>(x, hfw, arr_hf, a1, maxbf);
    k_dwt2<<<dim3(64, NB), 256, 0, stream>>>(a1, hfw, lfw, arr_hf, g2, maxbf);
    k_conv<<<dim3(4, 64, NB), 256, 0, stream>>>(arr_hf, g2, maxbf, cw, cb, out);
}

// Round 5
// 138.393 us; speedup vs baseline: 1.0023x; 1.0023x over previous
//
#include <hip/hip_runtime.h>

#define NB 16          // batch
#define NH 512
#define NW 512

// db2 decomposition filters
__device__ __constant__ float DLO[4] = {-0.12940952255092145f, 0.22414386804185735f, 0.836516303737469f, 0.48296291314469025f};
__device__ __constant__ float DHI[4] = {-0.48296291314469025f, 0.836516303737469f, -0.22414386804185735f, -0.12940952255092145f};

__device__ inline float wave_max(float v) {
    #pragma unroll
    for (int off = 32; off; off >>= 1) v = fmaxf(v, __shfl_xor(v, off, 64));
    return v;
}

// Level-1 DWT: x (512x512) -> a1 (256x256, scratch), (ad1,da1,dd1)*hfw into arr quadrants.
__global__ __launch_bounds__(256) void k_dwt1(const float* __restrict__ x,
                                              const float* __restrict__ hfw,
                                              float* __restrict__ arr_hf,
                                              float* __restrict__ a1,
                                              unsigned int* __restrict__ maxbuf) {
    int b = blockIdx.y;
    int idx = blockIdx.x * 256 + threadIdx.x;
    int r = idx >> 8, c = idx & 255;
    const float* xb = x + (size_t)b * (NH * NW);

    float X[4][4];
    if (r >= 1 && c >= 1) {
        const float* p = xb + (2 * r - 2) * 512 + (2 * c - 2);
        #pragma unroll
        for (int k = 0; k < 4; ++k) {
            float2 u0 = *(const float2*)(p + k * 512);
            float2 u1 = *(const float2*)(p + k * 512 + 2);
            X[k][0] = u0.x; X[k][1] = u0.y; X[k][2] = u1.x; X[k][3] = u1.y;
        }
    } else {
        #pragma unroll
        for (int k = 0; k < 4; ++k) {
            int rr = (2 * r - 2 + k + 512) & 511;
            #pragma unroll
            for (int l = 0; l < 4; ++l) {
                int cc = (2 * c - 2 + l + 512) & 511;
                X[k][l] = xb[rr * 512 + cc];
            }
        }
    }
    // lo[l] here equals original lo[3-l]; second stage uses reversed taps so results match.
    float lo[4], hi[4];
    #pragma unroll
    for (int l = 0; l < 4; ++l) {
        float alo = 0.f, ahi = 0.f;
        #pragma unroll
        for (int k = 0; k < 4; ++k) { alo += DLO[3 - k] * X[k][l]; ahi += DHI[3 - k] * X[k][l]; }
        lo[l] = alo; hi[l] = ahi;
    }
    float va = 0.f, vad = 0.f, vda = 0.f, vdd = 0.f;
    #pragma unroll
    for (int l = 0; l < 4; ++l) {
        va  += DLO[3 - l] * lo[l];
        vad += DHI[3 - l] * lo[l];
        vda += DLO[3 - l] * hi[l];
        vdd += DHI[3 - l] * hi[l];
    }

    a1[b * 65536 + r * 256 + c] = va;
    float* arr = arr_hf + (size_t)b * (512 * 512);
    int p_tr = r * 512 + (c + 256);
    int p_bl = (r + 256) * 512 + c;
    int p_br = (r + 256) * 512 + (c + 256);
    arr[p_tr] = vad * hfw[p_tr];
    arr[p_bl] = vda * hfw[p_bl];
    arr[p_br] = vdd * hfw[p_br];

    __shared__ float wmax[4][3];
    int wv = threadIdx.x >> 6, ln = threadIdx.x & 63;
    float m0 = wave_max(fabsf(vad));
    float m1 = wave_max(fabsf(vda));
    float m2 = wave_max(fabsf(vdd));
    if (ln == 0) { wmax[wv][0] = m0; wmax[wv][1] = m1; wmax[wv][2] = m2; }
    __syncthreads();
    if (threadIdx.x < 3) {
        int i = threadIdx.x;
        float m = fmaxf(fmaxf(wmax[0][i], wmax[1][i]), fmaxf(wmax[2][i], wmax[3][i]));
        atomicMax(maxbuf + b * 8 + i, __float_as_uint(m));
    }
}

// Level-2 DWT: a1 -> (a2,ad2,da2,dd2)*hfw into arr top-left 256x256; g2 = a2*lfw scratch.
__global__ __launch_bounds__(256) void k_dwt2(const float* __restrict__ a1,
                                              const float* __restrict__ hfw,
                                              const float* __restrict__ lfw,
                                              float* __restrict__ arr_hf,
                                              float* __restrict__ g2,
                                              unsigned int* __restrict__ maxbuf) {
    int b = blockIdx.y;
    int idx = blockIdx.x * 256 + threadIdx.x;
    int r = idx >> 7, c = idx & 127;
    const float* ab = a1 + b * 65536;

    float X[4][4];
    if (r >= 1 && c >= 1) {
        const float* p = ab + (2 * r - 2) * 256 + (2 * c - 2);
        #pragma unroll
        for (int k = 0; k < 4; ++k) {
            float2 u0 = *(const float2*)(p + k * 256);
            float2 u1 = *(const float2*)(p + k * 256 + 2);
            X[k][0] = u0.x; X[k][1] = u0.y; X[k][2] = u1.x; X[k][3] = u1.y;
        }
    } else {
        #pragma unroll
        for (int k = 0; k < 4; ++k) {
            int rr = (2 * r - 2 + k + 256) & 255;
            #pragma unroll
            for (int l = 0; l < 4; ++l) {
                int cc = (2 * c - 2 + l + 256) & 255;
                X[k][l] = ab[rr * 256 + cc];
            }
        }
    }
    float lo[4], hi[4];
    #pragma unroll
    for (int l = 0; l < 4; ++l) {
        float alo = 0.f, ahi = 0.f;
        #pragma unroll
        for (int k = 0; k < 4; ++k) { alo += DLO[3 - k] * X[k][l]; ahi += DHI[3 - k] * X[k][l]; }
        lo[l] = alo; hi[l] = ahi;
    }
    float va = 0.f, vad = 0.f, vda = 0.f, vdd = 0.f;
    #pragma unroll
    for (int l = 0; l < 4; ++l) {
        va  += DLO[3 - l] * lo[l];
        vad += DHI[3 - l] * lo[l];
        vda += DLO[3 - l] * hi[l];
        vdd += DHI[3 - l] * hi[l];
    }

    g2[b * 16384 + r * 128 + c] = va * lfw[r * 128 + c];
    float* arr = arr_hf + (size_t)b * (512 * 512);
    int p_tl = r * 512 + c;
    int p_tr = r * 512 + (c + 128);
    int p_bl = (r + 128) * 512 + c;
    int p_br = (r + 128) * 512 + (c + 128);
    arr[p_tl] = va  * hfw[p_tl];
    arr[p_tr] = vad * hfw[p_tr];
    arr[p_bl] = vda * hfw[p_bl];
    arr[p_br] = vdd * hfw[p_br];

    __shared__ float wmax[4][4];
    int wv = threadIdx.x >> 6, ln = threadIdx.x & 63;
    float m0 = wave_max(fabsf(va));
    float m1 = wave_max(fabsf(vad));
    float m2 = wave_max(fabsf(vda));
    float m3 = wave_max(fabsf(vdd));
    if (ln == 0) { wmax[wv][0] = m0; wmax[wv][1] = m1; wmax[wv][2] = m2; wmax[wv][3] = m3; }
    __syncthreads();
    if (threadIdx.x < 4) {
        int i = threadIdx.x;
        float m = fmaxf(fmaxf(wmax[0][i], wmax[1][i]), fmaxf(wmax[2][i], wmax[3][i]));
        atomicMax(maxbuf + b * 8 + 3 + i, __float_as_uint(m));
    }
}

// Fused: normalize (ch0 from arr_hf), bilinear of g2*inv_a2 (ch1), 3x3 conv 2->16, +bias.
// Tile 128w x 4h per 256-thread block. tid>>6 selects a 4-oc group (weights in regs);
// each lane handles two 4-wide px quads (rows rp, rp+2). 8 x dwordx4 stores/thread.
__global__ __launch_bounds__(256, 3) void k_conv(const float* __restrict__ arr_hf,
                                                 const float* __restrict__ g2,
                                                 const unsigned int* __restrict__ maxbuf,
                                                 const float* __restrict__ cw,
                                                 const float* __restrict__ cb,
                                                 float* __restrict__ out) {
    int b   = blockIdx.z;
    int th0 = blockIdx.y * 4;
    int tw0 = blockIdx.x * 128;
    int tid = threadIdx.x;
    int ocg  = tid >> 6;
    int lane = tid & 63;

    __shared__ __align__(16) float tile[2][6][132];

    // per-thread weights: oc in [ocg*4, ocg*4+4), layout cw[oc][ic][kh][kw]
    float wreg[72], breg[4];
    {
        const float4* wp = (const float4*)(cw + ocg * 72);   // 288B-aligned
        #pragma unroll
        for (int i = 0; i < 18; ++i) {
            float4 t = wp[i];
            wreg[4 * i] = t.x; wreg[4 * i + 1] = t.y; wreg[4 * i + 2] = t.z; wreg[4 * i + 3] = t.w;
        }
        #pragma unroll
        for (int o = 0; o < 4; ++o) breg[o] = cb[ocg * 4 + o];
    }

    const unsigned int* mb = maxbuf + b * 8;
    float inv_ad1 = 1.f / __uint_as_float(mb[0]);
    float inv_da1 = 1.f / __uint_as_float(mb[1]);
    float inv_dd1 = 1.f / __uint_as_float(mb[2]);
    float inv_a2  = 1.f / __uint_as_float(mb[3]);
    float inv_ad2 = 1.f / __uint_as_float(mb[4]);
    float inv_da2 = 1.f / __uint_as_float(mb[5]);
    float inv_dd2 = 1.f / __uint_as_float(mb[6]);

    const float* arr = arr_hf + (size_t)b * (512 * 512);
    const float* g2b = g2 + b * 16384;

    for (int i = tid; i < 6 * 130; i += 256) {
        int row = i / 130;
        int col = i - row * 130;
        int gh = th0 + row - 1;
        int gw = tw0 + col - 1;
        float v0 = 0.f, v1 = 0.f;
        if (gh >= 0 && gh < 512 && gw >= 0 && gw < 512) {
            // channel 0: (quad-tree * hfw) * inv(quadrant)
            float inv;
            if (gh < 256) {
                if (gw < 256) {
                    if (gh < 128) inv = (gw < 128) ? inv_a2 : inv_ad2;
                    else          inv = (gw < 128) ? inv_da2 : inv_dd2;
                } else inv = inv_ad1;
            } else inv = (gw < 256) ? inv_da1 : inv_dd1;
            v0 = arr[gh * 512 + gw] * inv;

            // channel 1: bilinear of (a2*lfw) then * inv_a2
            float sh = fminf(fmaxf(0.25f * (float)gh - 0.375f, 0.f), 127.f);
            float sw = fminf(fmaxf(0.25f * (float)gw - 0.375f, 0.f), 127.f);
            int r0 = (int)sh; float fr = sh - (float)r0; int r1 = min(r0 + 1, 127);
            int c0 = (int)sw; float fc = sw - (float)c0; int c1 = min(c0 + 1, 127);
            float g00 = g2b[r0 * 128 + c0];
            float g01 = g2b[r0 * 128 + c1];
            float g10 = g2b[r1 * 128 + c0];
            float g11 = g2b[r1 * 128 + c1];
            float t0 = g00 * (1.f - fr) + g10 * fr;
            float t1 = g01 * (1.f - fr) + g11 * fr;
            v1 = (t0 * (1.f - fc) + t1 * fc) * inv_a2;
        }
        tile[0][row][col] = v0;
        tile[1][row][col] = v1;
    }
    __syncthreads();

    int wq = lane & 31;   // w-quad: w0 = 4*wq
    int rp = lane >> 5;   // rows rp and rp+2

    float acc[4][8];      // [oc][2 rows x 4 px]
    #pragma unroll
    for (int o = 0; o < 4; ++o)
        #pragma unroll
        for (int j = 0; j < 8; ++j) acc[o][j] = breg[o];

    #pragma unroll
    for (int ic = 0; ic < 2; ++ic)
        #pragma unroll
        for (int kh = 0; kh < 3; ++kh) {
            const float* r0p = &tile[ic][rp + kh][4 * wq];
            const float* r1p = &tile[ic][rp + 2 + kh][4 * wq];
            float v[6], u[6];
            { float4 t = *(const float4*)r0p; v[0] = t.x; v[1] = t.y; v[2] = t.z; v[3] = t.w;
              float2 s = *(const float2*)(r0p + 4); v[4] = s.x; v[5] = s.y; }
            { float4 t = *(const float4*)r1p; u[0] = t.x; u[1] = t.y; u[2] = t.z; u[3] = t.w;
              float2 s = *(const float2*)(r1p + 4); u[4] = s.x; u[5] = s.y; }
            #pragma unroll
            for (int kw = 0; kw < 3; ++kw)
                #pragma unroll
                for (int o = 0; o < 4; ++o) {
                    float wv = wreg[o * 18 + ic * 9 + kh * 3 + kw];
                    #pragma unroll
                    for (int j = 0; j < 4; ++j) {
                        acc[o][j]     = fmaf(v[j + kw], wv, acc[o][j]);
                        acc[o][4 + j] = fmaf(u[j + kw], wv, acc[o][4 + j]);
                    }
                }
        }

    size_t plane = 512 * 512;
    float* ob = out + (size_t)(b * 16 + ocg * 4) * plane + (size_t)th0 * 512 + tw0 + 4 * wq;
    #pragma unroll
    for (int o = 0; o < 4; ++o) {
        #pragma unroll
        for (int h = 0; h < 2; ++h) {
            int row = rp + 2 * h;
            float4 val = make_float4(acc[o][4 * h], acc[o][4 * h + 1], acc[o][4 * h + 2], acc[o][4 * h + 3]);
            *(float4*)(ob + (size_t)o * plane + (size_t)row * 512) = val;
        }
    }
}

extern "C" void kernel_launch(void* const* d_in, const int* in_sizes, int n_in,
                              void* d_out, int out_size, void* d_ws, size_t ws_size,
                              hipStream_t stream) {
    const float* x   = (const float*)d_in[0];
    const float* hfw = (const float*)d_in[1];
    const float* lfw = (const float*)d_in[2];
    const float* cw  = (const float*)d_in[3];
    const float* cb  = (const float*)d_in[4];
    float* out = (float*)d_out;

    char* ws = (char*)d_ws;
    float* arr_hf       = (float*)(ws);                    // 16 MiB: 16 x 512 x 512 (pre-multiplied by hfw)
    float* a1           = (float*)(ws + 16777216);         //  4 MiB: 16 x 256 x 256
    float* g2           = (float*)(ws + 20971520);         //  1 MiB: 16 x 128 x 128 (a2 * lfw)
    unsigned int* maxbf = (unsigned int*)(ws + 22020096);  //  16 x 8 u32

    (void)hipMemsetAsync(maxbf, 0, NB * 8 * sizeof(unsigned int), stream);
    k_dwt1<<<dim3(256, NB), 256, 0, stream>>>(x, hfw, arr_hf, a1, maxbf);
    k_dwt2<<<dim3(64, NB), 256, 0, stream>>>(a1, hfw, lfw, arr_hf, g2, maxbf);
    k_conv<<<dim3(4, 128, NB), 256, 0, stream>>>(arr_hf, g2, maxbf, cw, cb, out);
}

// Round 7
// 114.921 us; speedup vs baseline: 1.2071x; 1.2042x over previous
//
#include <hip/hip_runtime.h>

#define NB 16          // batch
#define NH 512
#define NW 512

// db2 decomposition filters
__device__ __constant__ float DLO[4] = {-0.12940952255092145f, 0.22414386804185735f, 0.836516303737469f, 0.48296291314469025f};
__device__ __constant__ float DHI[4] = {-0.48296291314469025f, 0.836516303737469f, -0.22414386804185735f, -0.12940952255092145f};

__device__ inline float wave_max(float v) {
    #pragma unroll
    for (int off = 32; off; off >>= 1) v = fmaxf(v, __shfl_xor(v, off, 64));
    return v;
}

// Level-1 DWT: x (512x512) -> a1 (256x256, scratch), (ad1,da1,dd1)*hfw into arr quadrants.
__global__ __launch_bounds__(256) void k_dwt1(const float* __restrict__ x,
                                              const float* __restrict__ hfw,
                                              float* __restrict__ arr_hf,
                                              float* __restrict__ a1,
                                              unsigned int* __restrict__ maxbuf) {
    int b = blockIdx.y;
    int idx = blockIdx.x * 256 + threadIdx.x;
    int r = idx >> 8, c = idx & 255;
    const float* xb = x + (size_t)b * (NH * NW);

    float X[4][4];
    if (r >= 1 && c >= 1) {
        const float* p = xb + (2 * r - 2) * 512 + (2 * c - 2);
        #pragma unroll
        for (int k = 0; k < 4; ++k) {
            float2 u0 = *(const float2*)(p + k * 512);
            float2 u1 = *(const float2*)(p + k * 512 + 2);
            X[k][0] = u0.x; X[k][1] = u0.y; X[k][2] = u1.x; X[k][3] = u1.y;
        }
    } else {
        #pragma unroll
        for (int k = 0; k < 4; ++k) {
            int rr = (2 * r - 2 + k + 512) & 511;
            #pragma unroll
            for (int l = 0; l < 4; ++l) {
                int cc = (2 * c - 2 + l + 512) & 511;
                X[k][l] = xb[rr * 512 + cc];
            }
        }
    }
    // lo[l] here equals original lo[3-l]; second stage uses reversed taps so results match.
    float lo[4], hi[4];
    #pragma unroll
    for (int l = 0; l < 4; ++l) {
        float alo = 0.f, ahi = 0.f;
        #pragma unroll
        for (int k = 0; k < 4; ++k) { alo += DLO[3 - k] * X[k][l]; ahi += DHI[3 - k] * X[k][l]; }
        lo[l] = alo; hi[l] = ahi;
    }
    float va = 0.f, vad = 0.f, vda = 0.f, vdd = 0.f;
    #pragma unroll
    for (int l = 0; l < 4; ++l) {
        va  += DLO[3 - l] * lo[l];
        vad += DHI[3 - l] * lo[l];
        vda += DLO[3 - l] * hi[l];
        vdd += DHI[3 - l] * hi[l];
    }

    a1[b * 65536 + r * 256 + c] = va;
    float* arr = arr_hf + (size_t)b * (512 * 512);
    int p_tr = r * 512 + (c + 256);
    int p_bl = (r + 256) * 512 + c;
    int p_br = (r + 256) * 512 + (c + 256);
    arr[p_tr] = vad * hfw[p_tr];
    arr[p_bl] = vda * hfw[p_bl];
    arr[p_br] = vdd * hfw[p_br];

    __shared__ float wmax[4][3];
    int wv = threadIdx.x >> 6, ln = threadIdx.x & 63;
    float m0 = wave_max(fabsf(vad));
    float m1 = wave_max(fabsf(vda));
    float m2 = wave_max(fabsf(vdd));
    if (ln == 0) { wmax[wv][0] = m0; wmax[wv][1] = m1; wmax[wv][2] = m2; }
    __syncthreads();
    if (threadIdx.x < 3) {
        int i = threadIdx.x;
        float m = fmaxf(fmaxf(wmax[0][i], wmax[1][i]), fmaxf(wmax[2][i], wmax[3][i]));
        atomicMax(maxbuf + b * 8 + i, __float_as_uint(m));
    }
}

// Level-2 DWT: a1 -> (a2,ad2,da2,dd2)*hfw into arr top-left 256x256; g2 = a2*lfw scratch.
__global__ __launch_bounds__(256) void k_dwt2(const float* __restrict__ a1,
                                              const float* __restrict__ hfw,
                                              const float* __restrict__ lfw,
                                              float* __restrict__ arr_hf,
                                              float* __restrict__ g2,
                                              unsigned int* __restrict__ maxbuf) {
    int b = blockIdx.y;
    int idx = blockIdx.x * 256 + threadIdx.x;
    int r = idx >> 7, c = idx & 127;
    const float* ab = a1 + b * 65536;

    float X[4][4];
    if (r >= 1 && c >= 1) {
        const float* p = ab + (2 * r - 2) * 256 + (2 * c - 2);
        #pragma unroll
        for (int k = 0; k < 4; ++k) {
            float2 u0 = *(const float2*)(p + k * 256);
            float2 u1 = *(const float2*)(p + k * 256 + 2);
            X[k][0] = u0.x; X[k][1] = u0.y; X[k][2] = u1.x; X[k][3] = u1.y;
        }
    } else {
        #pragma unroll
        for (int k = 0; k < 4; ++k) {
            int rr = (2 * r - 2 + k + 256) & 255;
            #pragma unroll
            for (int l = 0; l < 4; ++l) {
                int cc = (2 * c - 2 + l + 256) & 255;
                X[k][l] = ab[rr * 256 + cc];
            }
        }
    }
    float lo[4], hi[4];
    #pragma unroll
    for (int l = 0; l < 4; ++l) {
        float alo = 0.f, ahi = 0.f;
        #pragma unroll
        for (int k = 0; k < 4; ++k) { alo += DLO[3 - k] * X[k][l]; ahi += DHI[3 - k] * X[k][l]; }
        lo[l] = alo; hi[l] = ahi;
    }
    float va = 0.f, vad = 0.f, vda = 0.f, vdd = 0.f;
    #pragma unroll
    for (int l = 0; l < 4; ++l) {
        va  += DLO[3 - l] * lo[l];
        vad += DHI[3 - l] * lo[l];
        vda += DLO[3 - l] * hi[l];
        vdd += DHI[3 - l] * hi[l];
    }

    g2[b * 16384 + r * 128 + c] = va * lfw[r * 128 + c];
    float* arr = arr_hf + (size_t)b * (512 * 512);
    int p_tl = r * 512 + c;
    int p_tr = r * 512 + (c + 128);
    int p_bl = (r + 128) * 512 + c;
    int p_br = (r + 128) * 512 + (c + 128);
    arr[p_tl] = va  * hfw[p_tl];
    arr[p_tr] = vad * hfw[p_tr];
    arr[p_bl] = vda * hfw[p_bl];
    arr[p_br] = vdd * hfw[p_br];

    __shared__ float wmax[4][4];
    int wv = threadIdx.x >> 6, ln = threadIdx.x & 63;
    float m0 = wave_max(fabsf(va));
    float m1 = wave_max(fabsf(vad));
    float m2 = wave_max(fabsf(vda));
    float m3 = wave_max(fabsf(vdd));
    if (ln == 0) { wmax[wv][0] = m0; wmax[wv][1] = m1; wmax[wv][2] = m2; wmax[wv][3] = m3; }
    __syncthreads();
    if (threadIdx.x < 4) {
        int i = threadIdx.x;
        float m = fmaxf(fmaxf(wmax[0][i], wmax[1][i]), fmaxf(wmax[2][i], wmax[3][i]));
        atomicMax(maxbuf + b * 8 + 3 + i, __float_as_uint(m));
    }
}

// Fused: normalize (ch0 from arr_hf), bilinear of g2*inv_a2 (ch1), 3x3 conv 2->16, +bias.
// Tile 128w x 4h per 256-thread block. Wave ocg=tid>>6 owns 4 oc; weights live in LDS
// (transposed [ic][kh][oc][kw]) and are broadcast-read 12-at-a-time per (ic,kh) --
// keeps VGPR low for more waves/SIMD than wreg[72].
__global__ __launch_bounds__(256) void k_conv(const float* __restrict__ arr_hf,
                                              const float* __restrict__ g2,
                                              const unsigned int* __restrict__ maxbuf,
                                              const float* __restrict__ cw,
                                              const float* __restrict__ cb,
                                              float* __restrict__ out) {
    int b   = blockIdx.z;
    int th0 = blockIdx.y * 4;
    int tw0 = blockIdx.x * 128;
    int tid = threadIdx.x;
    int ocg  = tid >> 6;
    int lane = tid & 63;

    __shared__ __align__(16) float tile[2][6][132];
    __shared__ __align__(16) float lds_w[288];   // [ic][kh][oc][kw]
    __shared__ float lds_b[16];

    for (int i = tid; i < 288; i += 256) {       // 256 threads, 288 weights: 2 iterations
        float v = cw[i];
        int oc = i / 18, rem = i - oc * 18;
        int ic = rem / 9;  rem -= ic * 9;
        int kh = rem / 3;  int kw = rem - kh * 3;
        lds_w[((ic * 3 + kh) * 16 + oc) * 3 + kw] = v;
    }
    if (tid < 16) lds_b[tid] = cb[tid];

    const unsigned int* mb = maxbuf + b * 8;
    float inv_ad1 = 1.f / __uint_as_float(mb[0]);
    float inv_da1 = 1.f / __uint_as_float(mb[1]);
    float inv_dd1 = 1.f / __uint_as_float(mb[2]);
    float inv_a2  = 1.f / __uint_as_float(mb[3]);
    float inv_ad2 = 1.f / __uint_as_float(mb[4]);
    float inv_da2 = 1.f / __uint_as_float(mb[5]);
    float inv_dd2 = 1.f / __uint_as_float(mb[6]);

    const float* arr = arr_hf + (size_t)b * (512 * 512);
    const float* g2b = g2 + b * 16384;

    for (int i = tid; i < 6 * 130; i += 256) {
        int row = i / 130;
        int col = i - row * 130;
        int gh = th0 + row - 1;
        int gw = tw0 + col - 1;
        float v0 = 0.f, v1 = 0.f;
        if (gh >= 0 && gh < 512 && gw >= 0 && gw < 512) {
            // channel 0: (quad-tree * hfw) * inv(quadrant)
            float inv;
            if (gh < 256) {
                if (gw < 256) {
                    if (gh < 128) inv = (gw < 128) ? inv_a2 : inv_ad2;
                    else          inv = (gw < 128) ? inv_da2 : inv_dd2;
                } else inv = inv_ad1;
            } else inv = (gw < 256) ? inv_da1 : inv_dd1;
            v0 = arr[gh * 512 + gw] * inv;

            // channel 1: bilinear of (a2*lfw) then * inv_a2
            float sh = fminf(fmaxf(0.25f * (float)gh - 0.375f, 0.f), 127.f);
            float sw = fminf(fmaxf(0.25f * (float)gw - 0.375f, 0.f), 127.f);
            int r0 = (int)sh; float fr = sh - (float)r0; int r1 = min(r0 + 1, 127);
            int c0 = (int)sw; float fc = sw - (float)c0; int c1 = min(c0 + 1, 127);
            float g00 = g2b[r0 * 128 + c0];
            float g01 = g2b[r0 * 128 + c1];
            float g10 = g2b[r1 * 128 + c0];
            float g11 = g2b[r1 * 128 + c1];
            float t0 = g00 * (1.f - fr) + g10 * fr;
            float t1 = g01 * (1.f - fr) + g11 * fr;
            v1 = (t0 * (1.f - fc) + t1 * fc) * inv_a2;
        }
        tile[0][row][col] = v0;
        tile[1][row][col] = v1;
    }
    __syncthreads();

    int wq = lane & 31;   // w-quad: w0 = 4*wq
    int rp = lane >> 5;   // rows rp and rp+2

    float bv[4];
    #pragma unroll
    for (int o = 0; o < 4; ++o) bv[o] = lds_b[ocg * 4 + o];

    float acc[4][8];      // [oc][2 rows x 4 px]
    #pragma unroll
    for (int o = 0; o < 4; ++o)
        #pragma unroll
        for (int j = 0; j < 8; ++j) acc[o][j] = bv[o];

    #pragma unroll
    for (int ic = 0; ic < 2; ++ic)
        #pragma unroll
        for (int kh = 0; kh < 3; ++kh) {
            // broadcast-read this (ic,kh)'s 4oc x 3kw weights: 3 x ds_read_b128
            float wv[12];
            {
                const float* wp = &lds_w[((ic * 3 + kh) * 16 + ocg * 4) * 3];
                #pragma unroll
                for (int q = 0; q < 3; ++q) {
                    float4 t = *(const float4*)(wp + 4 * q);
                    wv[4 * q] = t.x; wv[4 * q + 1] = t.y; wv[4 * q + 2] = t.z; wv[4 * q + 3] = t.w;
                }
            }
            const float* r0p = &tile[ic][rp + kh][4 * wq];
            const float* r1p = &tile[ic][rp + 2 + kh][4 * wq];
            float v[6], u[6];
            { float4 t = *(const float4*)r0p; v[0] = t.x; v[1] = t.y; v[2] = t.z; v[3] = t.w;
              float2 s = *(const float2*)(r0p + 4); v[4] = s.x; v[5] = s.y; }
            { float4 t = *(const float4*)r1p; u[0] = t.x; u[1] = t.y; u[2] = t.z; u[3] = t.w;
              float2 s = *(const float2*)(r1p + 4); u[4] = s.x; u[5] = s.y; }
            #pragma unroll
            for (int kw = 0; kw < 3; ++kw)
                #pragma unroll
                for (int o = 0; o < 4; ++o) {
                    float wvv = wv[o * 3 + kw];
                    #pragma unroll
                    for (int j = 0; j < 4; ++j) {
                        acc[o][j]     = fmaf(v[j + kw], wvv, acc[o][j]);
                        acc[o][4 + j] = fmaf(u[j + kw], wvv, acc[o][4 + j]);
                    }
                }
        }

    size_t plane = 512 * 512;
    float* ob = out + (size_t)(b * 16 + ocg * 4) * plane + (size_t)th0 * 512 + tw0 + 4 * wq;
    #pragma unroll
    for (int o = 0; o < 4; ++o) {
        #pragma unroll
        for (int h = 0; h < 2; ++h) {
            int row = rp + 2 * h;
            float4 val = make_float4(acc[o][4 * h], acc[o][4 * h + 1], acc[o][4 * h + 2], acc[o][4 * h + 3]);
            *(float4*)(ob + (size_t)o * plane + (size_t)row * 512) = val;
        }
    }
}

extern "C" void kernel_launch(void* const* d_in, const int* in_sizes, int n_in,
                              void* d_out, int out_size, void* d_ws, size_t ws_size,
                              hipStream_t stream) {
    const float* x   = (const float*)d_in[0];
    const float* hfw = (const float*)d_in[1];
    const float* lfw = (const float*)d_in[2];
    const float* cw  = (const float*)d_in[3];
    const float* cb  = (const float*)d_in[4];
    float* out = (float*)d_out;

    char* ws = (char*)d_ws;
    float* arr_hf       = (float*)(ws);                    // 16 MiB: 16 x 512 x 512 (pre-multiplied by hfw)
    float* a1           = (float*)(ws + 16777216);         //  4 MiB: 16 x 256 x 256
    float* g2           = (float*)(ws + 20971520);         //  1 MiB: 16 x 128 x 128 (a2 * lfw)
    unsigned int* maxbf = (unsigned int*)(ws + 22020096);  //  16 x 8 u32

    (void)hipMemsetAsync(maxbf, 0, NB * 8 * sizeof(unsigned int), stream);
    k_dwt1<<<dim3(256, NB), 256, 0, stream>>>(x, hfw, arr_hf, a1, maxbf);
    k_dwt2<<<dim3(64, NB), 256, 0, stream>>>(a1, hfw, lfw, arr_hf, g2, maxbf);
    k_conv<<<dim3(4, 128, NB), 256, 0, stream>>>(arr_hf, g2, maxbf, cw, cb, out);
}

// Round 8
// 110.726 us; speedup vs baseline: 1.2528x; 1.0379x over previous
//
#include <hip/hip_runtime.h>

#define NB 16          // batch
#define NH 512
#define NW 512

// db2 decomposition filters
__device__ __constant__ float DLO[4] = {-0.12940952255092145f, 0.22414386804185735f, 0.836516303737469f, 0.48296291314469025f};
__device__ __constant__ float DHI[4] = {-0.48296291314469025f, 0.836516303737469f, -0.22414386804185735f, -0.12940952255092145f};

__device__ inline float wave_max(float v) {
    #pragma unroll
    for (int off = 32; off; off >>= 1) v = fmaxf(v, __shfl_xor(v, off, 64));
    return v;
}

// Level-1 DWT: x (512x512) -> a1 (256x256, scratch), (ad1,da1,dd1)*hfw into arr quadrants.
__global__ __launch_bounds__(256) void k_dwt1(const float* __restrict__ x,
                                              const float* __restrict__ hfw,
                                              float* __restrict__ arr_hf,
                                              float* __restrict__ a1,
                                              unsigned int* __restrict__ maxbuf) {
    int b = blockIdx.y;
    int idx = blockIdx.x * 256 + threadIdx.x;
    int r = idx >> 8, c = idx & 255;
    const float* xb = x + (size_t)b * (NH * NW);

    float X[4][4];
    if (r >= 1 && c >= 1) {
        const float* p = xb + (2 * r - 2) * 512 + (2 * c - 2);
        #pragma unroll
        for (int k = 0; k < 4; ++k) {
            float2 u0 = *(const float2*)(p + k * 512);
            float2 u1 = *(const float2*)(p + k * 512 + 2);
            X[k][0] = u0.x; X[k][1] = u0.y; X[k][2] = u1.x; X[k][3] = u1.y;
        }
    } else {
        #pragma unroll
        for (int k = 0; k < 4; ++k) {
            int rr = (2 * r - 2 + k + 512) & 511;
            #pragma unroll
            for (int l = 0; l < 4; ++l) {
                int cc = (2 * c - 2 + l + 512) & 511;
                X[k][l] = xb[rr * 512 + cc];
            }
        }
    }
    // lo[l] here equals original lo[3-l]; second stage uses reversed taps so results match.
    float lo[4], hi[4];
    #pragma unroll
    for (int l = 0; l < 4; ++l) {
        float alo = 0.f, ahi = 0.f;
        #pragma unroll
        for (int k = 0; k < 4; ++k) { alo += DLO[3 - k] * X[k][l]; ahi += DHI[3 - k] * X[k][l]; }
        lo[l] = alo; hi[l] = ahi;
    }
    float va = 0.f, vad = 0.f, vda = 0.f, vdd = 0.f;
    #pragma unroll
    for (int l = 0; l < 4; ++l) {
        va  += DLO[3 - l] * lo[l];
        vad += DHI[3 - l] * lo[l];
        vda += DLO[3 - l] * hi[l];
        vdd += DHI[3 - l] * hi[l];
    }

    a1[b * 65536 + r * 256 + c] = va;
    float* arr = arr_hf + (size_t)b * (512 * 512);
    int p_tr = r * 512 + (c + 256);
    int p_bl = (r + 256) * 512 + c;
    int p_br = (r + 256) * 512 + (c + 256);
    arr[p_tr] = vad * hfw[p_tr];
    arr[p_bl] = vda * hfw[p_bl];
    arr[p_br] = vdd * hfw[p_br];

    __shared__ float wmax[4][3];
    int wv = threadIdx.x >> 6, ln = threadIdx.x & 63;
    float m0 = wave_max(fabsf(vad));
    float m1 = wave_max(fabsf(vda));
    float m2 = wave_max(fabsf(vdd));
    if (ln == 0) { wmax[wv][0] = m0; wmax[wv][1] = m1; wmax[wv][2] = m2; }
    __syncthreads();
    if (threadIdx.x < 3) {
        int i = threadIdx.x;
        float m = fmaxf(fmaxf(wmax[0][i], wmax[1][i]), fmaxf(wmax[2][i], wmax[3][i]));
        atomicMax(maxbuf + b * 8 + i, __float_as_uint(m));
    }
}

// Level-2 DWT: a1 -> (a2,ad2,da2,dd2)*hfw into arr top-left 256x256; g2 = a2*lfw scratch.
__global__ __launch_bounds__(256) void k_dwt2(const float* __restrict__ a1,
                                              const float* __restrict__ hfw,
                                              const float* __restrict__ lfw,
                                              float* __restrict__ arr_hf,
                                              float* __restrict__ g2,
                                              unsigned int* __restrict__ maxbuf) {
    int b = blockIdx.y;
    int idx = blockIdx.x * 256 + threadIdx.x;
    int r = idx >> 7, c = idx & 127;
    const float* ab = a1 + b * 65536;

    float X[4][4];
    if (r >= 1 && c >= 1) {
        const float* p = ab + (2 * r - 2) * 256 + (2 * c - 2);
        #pragma unroll
        for (int k = 0; k < 4; ++k) {
            float2 u0 = *(const float2*)(p + k * 256);
            float2 u1 = *(const float2*)(p + k * 256 + 2);
            X[k][0] = u0.x; X[k][1] = u0.y; X[k][2] = u1.x; X[k][3] = u1.y;
        }
    } else {
        #pragma unroll
        for (int k = 0; k < 4; ++k) {
            int rr = (2 * r - 2 + k + 256) & 255;
            #pragma unroll
            for (int l = 0; l < 4; ++l) {
                int cc = (2 * c - 2 + l + 256) & 255;
                X[k][l] = ab[rr * 256 + cc];
            }
        }
    }
    float lo[4], hi[4];
    #pragma unroll
    for (int l = 0; l < 4; ++l) {
        float alo = 0.f, ahi = 0.f;
        #pragma unroll
        for (int k = 0; k < 4; ++k) { alo += DLO[3 - k] * X[k][l]; ahi += DHI[3 - k] * X[k][l]; }
        lo[l] = alo; hi[l] = ahi;
    }
    float va = 0.f, vad = 0.f, vda = 0.f, vdd = 0.f;
    #pragma unroll
    for (int l = 0; l < 4; ++l) {
        va  += DLO[3 - l] * lo[l];
        vad += DHI[3 - l] * lo[l];
        vda += DLO[3 - l] * hi[l];
        vdd += DHI[3 - l] * hi[l];
    }

    g2[b * 16384 + r * 128 + c] = va * lfw[r * 128 + c];
    float* arr = arr_hf + (size_t)b * (512 * 512);
    int p_tl = r * 512 + c;
    int p_tr = r * 512 + (c + 128);
    int p_bl = (r + 128) * 512 + c;
    int p_br = (r + 128) * 512 + (c + 128);
    arr[p_tl] = va  * hfw[p_tl];
    arr[p_tr] = vad * hfw[p_tr];
    arr[p_bl] = vda * hfw[p_bl];
    arr[p_br] = vdd * hfw[p_br];

    __shared__ float wmax[4][4];
    int wv = threadIdx.x >> 6, ln = threadIdx.x & 63;
    float m0 = wave_max(fabsf(va));
    float m1 = wave_max(fabsf(vad));
    float m2 = wave_max(fabsf(vda));
    float m3 = wave_max(fabsf(vdd));
    if (ln == 0) { wmax[wv][0] = m0; wmax[wv][1] = m1; wmax[wv][2] = m2; wmax[wv][3] = m3; }
    __syncthreads();
    if (threadIdx.x < 4) {
        int i = threadIdx.x;
        float m = fmaxf(fmaxf(wmax[0][i], wmax[1][i]), fmaxf(wmax[2][i], wmax[3][i]));
        atomicMax(maxbuf + b * 8 + 3 + i, __float_as_uint(m));
    }
}

// Fused: normalize (ch0 from arr_hf), bilinear of g2*inv_a2 (ch1), 3x3 conv 2->16, +bias.
// Tile 128w x 8h per 256-thread block. EVERY thread computes ALL 16 oc for one 4-px quad:
// thread -> (row = tid>>5 in 0..7, wq = tid&31). Weights are thread-independent ->
// compiler scalarizes cw[] reads into s_load (SGPR), no LDS, v_fmac with SGPR operand.
// LDS reads: 12/thread (6 x b128+b64 tile rows) for 64 px*oc outputs.
__global__ __launch_bounds__(256) void k_conv(const float* __restrict__ arr_hf,
                                              const float* __restrict__ g2,
                                              const unsigned int* __restrict__ maxbuf,
                                              const float* __restrict__ cw,
                                              const float* __restrict__ cb,
                                              float* __restrict__ out) {
    int b   = blockIdx.z;
    int th0 = blockIdx.y * 8;
    int tw0 = blockIdx.x * 128;
    int tid = threadIdx.x;

    __shared__ __align__(16) float tile[2][10][132];

    const unsigned int* mb = maxbuf + b * 8;
    float inv_ad1 = 1.f / __uint_as_float(mb[0]);
    float inv_da1 = 1.f / __uint_as_float(mb[1]);
    float inv_dd1 = 1.f / __uint_as_float(mb[2]);
    float inv_a2  = 1.f / __uint_as_float(mb[3]);
    float inv_ad2 = 1.f / __uint_as_float(mb[4]);
    float inv_da2 = 1.f / __uint_as_float(mb[5]);
    float inv_dd2 = 1.f / __uint_as_float(mb[6]);

    const float* arr = arr_hf + (size_t)b * (512 * 512);
    const float* g2b = g2 + b * 16384;

    for (int i = tid; i < 10 * 130; i += 256) {
        int row = i / 130;
        int col = i - row * 130;
        int gh = th0 + row - 1;
        int gw = tw0 + col - 1;
        float v0 = 0.f, v1 = 0.f;
        if (gh >= 0 && gh < 512 && gw >= 0 && gw < 512) {
            // channel 0: (quad-tree * hfw) * inv(quadrant)
            float inv;
            if (gh < 256) {
                if (gw < 256) {
                    if (gh < 128) inv = (gw < 128) ? inv_a2 : inv_ad2;
                    else          inv = (gw < 128) ? inv_da2 : inv_dd2;
                } else inv = inv_ad1;
            } else inv = (gw < 256) ? inv_da1 : inv_dd1;
            v0 = arr[gh * 512 + gw] * inv;

            // channel 1: bilinear of (a2*lfw) then * inv_a2
            float sh = fminf(fmaxf(0.25f * (float)gh - 0.375f, 0.f), 127.f);
            float sw = fminf(fmaxf(0.25f * (float)gw - 0.375f, 0.f), 127.f);
            int r0 = (int)sh; float fr = sh - (float)r0; int r1 = min(r0 + 1, 127);
            int c0 = (int)sw; float fc = sw - (float)c0; int c1 = min(c0 + 1, 127);
            float g00 = g2b[r0 * 128 + c0];
            float g01 = g2b[r0 * 128 + c1];
            float g10 = g2b[r1 * 128 + c0];
            float g11 = g2b[r1 * 128 + c1];
            float t0 = g00 * (1.f - fr) + g10 * fr;
            float t1 = g01 * (1.f - fr) + g11 * fr;
            v1 = (t0 * (1.f - fc) + t1 * fc) * inv_a2;
        }
        tile[0][row][col] = v0;
        tile[1][row][col] = v1;
    }
    __syncthreads();

    int wq  = tid & 31;   // w-quad: w0 = 4*wq
    int row = tid >> 5;   // output row within tile: 0..7

    float acc[16][4];
    #pragma unroll
    for (int oc = 0; oc < 16; ++oc) {
        float bvv = cb[oc];          // uniform -> s_load
        #pragma unroll
        for (int j = 0; j < 4; ++j) acc[oc][j] = bvv;
    }

    #pragma unroll
    for (int ic = 0; ic < 2; ++ic)
        #pragma unroll
        for (int kh = 0; kh < 3; ++kh) {
            const float* rp_ = &tile[ic][row + kh][4 * wq];
            float v[6];
            { float4 t = *(const float4*)rp_; v[0] = t.x; v[1] = t.y; v[2] = t.z; v[3] = t.w;
              float2 s = *(const float2*)(rp_ + 4); v[4] = s.x; v[5] = s.y; }
            #pragma unroll
            for (int kw = 0; kw < 3; ++kw)
                #pragma unroll
                for (int oc = 0; oc < 16; ++oc) {
                    float wv = cw[oc * 18 + ic * 9 + kh * 3 + kw];   // uniform -> s_load
                    #pragma unroll
                    for (int j = 0; j < 4; ++j)
                        acc[oc][j] = fmaf(v[j + kw], wv, acc[oc][j]);
                }
        }

    size_t plane = 512 * 512;
    float* ob = out + (size_t)(b * 16) * plane + (size_t)(th0 + row) * 512 + tw0 + 4 * wq;
    #pragma unroll
    for (int oc = 0; oc < 16; ++oc) {
        float4 val = make_float4(acc[oc][0], acc[oc][1], acc[oc][2], acc[oc][3]);
        *(float4*)(ob + (size_t)oc * plane) = val;
    }
}

extern "C" void kernel_launch(void* const* d_in, const int* in_sizes, int n_in,
                              void* d_out, int out_size, void* d_ws, size_t ws_size,
                              hipStream_t stream) {
    const float* x   = (const float*)d_in[0];
    const float* hfw = (const float*)d_in[1];
    const float* lfw = (const float*)d_in[2];
    const float* cw  = (const float*)d_in[3];
    const float* cb  = (const float*)d_in[4];
    float* out = (float*)d_out;

    char* ws = (char*)d_ws;
    float* arr_hf       = (float*)(ws);                    // 16 MiB: 16 x 512 x 512 (pre-multiplied by hfw)
    float* a1           = (float*)(ws + 16777216);         //  4 MiB: 16 x 256 x 256
    float* g2           = (float*)(ws + 20971520);         //  1 MiB: 16 x 128 x 128 (a2 * lfw)
    unsigned int* maxbf = (unsigned int*)(ws + 22020096);  //  16 x 8 u32

    (void)hipMemsetAsync(maxbf, 0, NB * 8 * sizeof(unsigned int), stream);
    k_dwt1<<<dim3(256, NB), 256, 0, stream>>>(x, hfw, arr_hf, a1, maxbf);
    k_dwt2<<<dim3(64, NB), 256, 0, stream>>>(a1, hfw, lfw, arr_hf, g2, maxbf);
    k_conv<<<dim3(4, 64, NB), 256, 0, stream>>>(arr_hf, g2, maxbf, cw, cb, out);
}

// Round 9
// 99.305 us; speedup vs baseline: 1.3969x; 1.1150x over previous
//
#include <hip/hip_runtime.h>

#define NB 16          // batch
#define NH 512
#define NW 512

// db2 decomposition filters
__device__ __constant__ float DLO[4] = {-0.12940952255092145f, 0.22414386804185735f, 0.836516303737469f, 0.48296291314469025f};
__device__ __constant__ float DHI[4] = {-0.48296291314469025f, 0.836516303737469f, -0.22414386804185735f, -0.12940952255092145f};

__device__ inline float wave_max(float v) {
    #pragma unroll
    for (int off = 32; off; off >>= 1) v = fmaxf(v, __shfl_xor(v, off, 64));
    return v;
}

// Level-1 DWT: x (512x512) -> a1 (256x256, scratch), (ad1,da1,dd1)*hfw into arr quadrants.
__global__ __launch_bounds__(256) void k_dwt1(const float* __restrict__ x,
                                              const float* __restrict__ hfw,
                                              float* __restrict__ arr_hf,
                                              float* __restrict__ a1,
                                              unsigned int* __restrict__ maxbuf) {
    int b = blockIdx.y;
    int idx = blockIdx.x * 256 + threadIdx.x;
    int r = idx >> 8, c = idx & 255;
    const float* xb = x + (size_t)b * (NH * NW);

    float X[4][4];
    if (r >= 1 && c >= 1) {
        const float* p = xb + (2 * r - 2) * 512 + (2 * c - 2);
        #pragma unroll
        for (int k = 0; k < 4; ++k) {
            float2 u0 = *(const float2*)(p + k * 512);
            float2 u1 = *(const float2*)(p + k * 512 + 2);
            X[k][0] = u0.x; X[k][1] = u0.y; X[k][2] = u1.x; X[k][3] = u1.y;
        }
    } else {
        #pragma unroll
        for (int k = 0; k < 4; ++k) {
            int rr = (2 * r - 2 + k + 512) & 511;
            #pragma unroll
            for (int l = 0; l < 4; ++l) {
                int cc = (2 * c - 2 + l + 512) & 511;
                X[k][l] = xb[rr * 512 + cc];
            }
        }
    }
    // lo[l] here equals original lo[3-l]; second stage uses reversed taps so results match.
    float lo[4], hi[4];
    #pragma unroll
    for (int l = 0; l < 4; ++l) {
        float alo = 0.f, ahi = 0.f;
        #pragma unroll
        for (int k = 0; k < 4; ++k) { alo += DLO[3 - k] * X[k][l]; ahi += DHI[3 - k] * X[k][l]; }
        lo[l] = alo; hi[l] = ahi;
    }
    float va = 0.f, vad = 0.f, vda = 0.f, vdd = 0.f;
    #pragma unroll
    for (int l = 0; l < 4; ++l) {
        va  += DLO[3 - l] * lo[l];
        vad += DHI[3 - l] * lo[l];
        vda += DLO[3 - l] * hi[l];
        vdd += DHI[3 - l] * hi[l];
    }

    a1[b * 65536 + r * 256 + c] = va;
    float* arr = arr_hf + (size_t)b * (512 * 512);
    int p_tr = r * 512 + (c + 256);
    int p_bl = (r + 256) * 512 + c;
    int p_br = (r + 256) * 512 + (c + 256);
    arr[p_tr] = vad * hfw[p_tr];
    arr[p_bl] = vda * hfw[p_bl];
    arr[p_br] = vdd * hfw[p_br];

    __shared__ float wmax[4][3];
    int wv = threadIdx.x >> 6, ln = threadIdx.x & 63;
    float m0 = wave_max(fabsf(vad));
    float m1 = wave_max(fabsf(vda));
    float m2 = wave_max(fabsf(vdd));
    if (ln == 0) { wmax[wv][0] = m0; wmax[wv][1] = m1; wmax[wv][2] = m2; }
    __syncthreads();
    if (threadIdx.x < 3) {
        int i = threadIdx.x;
        float m = fmaxf(fmaxf(wmax[0][i], wmax[1][i]), fmaxf(wmax[2][i], wmax[3][i]));
        atomicMax(maxbuf + b * 8 + i, __float_as_uint(m));
    }
}

// Level-2 DWT: a1 -> (a2,ad2,da2,dd2)*hfw into arr top-left 256x256; g2 = a2*lfw scratch.
__global__ __launch_bounds__(256) void k_dwt2(const float* __restrict__ a1,
                                              const float* __restrict__ hfw,
                                              const float* __restrict__ lfw,
                                              float* __restrict__ arr_hf,
                                              float* __restrict__ g2,
                                              unsigned int* __restrict__ maxbuf) {
    int b = blockIdx.y;
    int idx = blockIdx.x * 256 + threadIdx.x;
    int r = idx >> 7, c = idx & 127;
    const float* ab = a1 + b * 65536;

    float X[4][4];
    if (r >= 1 && c >= 1) {
        const float* p = ab + (2 * r - 2) * 256 + (2 * c - 2);
        #pragma unroll
        for (int k = 0; k < 4; ++k) {
            float2 u0 = *(const float2*)(p + k * 256);
            float2 u1 = *(const float2*)(p + k * 256 + 2);
            X[k][0] = u0.x; X[k][1] = u0.y; X[k][2] = u1.x; X[k][3] = u1.y;
        }
    } else {
        #pragma unroll
        for (int k = 0; k < 4; ++k) {
            int rr = (2 * r - 2 + k + 256) & 255;
            #pragma unroll
            for (int l = 0; l < 4; ++l) {
                int cc = (2 * c - 2 + l + 256) & 255;
                X[k][l] = ab[rr * 256 + cc];
            }
        }
    }
    float lo[4], hi[4];
    #pragma unroll
    for (int l = 0; l < 4; ++l) {
        float alo = 0.f, ahi = 0.f;
        #pragma unroll
        for (int k = 0; k < 4; ++k) { alo += DLO[3 - k] * X[k][l]; ahi += DHI[3 - k] * X[k][l]; }
        lo[l] = alo; hi[l] = ahi;
    }
    float va = 0.f, vad = 0.f, vda = 0.f, vdd = 0.f;
    #pragma unroll
    for (int l = 0; l < 4; ++l) {
        va  += DLO[3 - l] * lo[l];
        vad += DHI[3 - l] * lo[l];
        vda += DLO[3 - l] * hi[l];
        vdd += DHI[3 - l] * hi[l];
    }

    g2[b * 16384 + r * 128 + c] = va * lfw[r * 128 + c];
    float* arr = arr_hf + (size_t)b * (512 * 512);
    int p_tl = r * 512 + c;
    int p_tr = r * 512 + (c + 128);
    int p_bl = (r + 128) * 512 + c;
    int p_br = (r + 128) * 512 + (c + 128);
    arr[p_tl] = va  * hfw[p_tl];
    arr[p_tr] = vad * hfw[p_tr];
    arr[p_bl] = vda * hfw[p_bl];
    arr[p_br] = vdd * hfw[p_br];

    __shared__ float wmax[4][4];
    int wv = threadIdx.x >> 6, ln = threadIdx.x & 63;
    float m0 = wave_max(fabsf(va));
    float m1 = wave_max(fabsf(vad));
    float m2 = wave_max(fabsf(vda));
    float m3 = wave_max(fabsf(vdd));
    if (ln == 0) { wmax[wv][0] = m0; wmax[wv][1] = m1; wmax[wv][2] = m2; wmax[wv][3] = m3; }
    __syncthreads();
    if (threadIdx.x < 4) {
        int i = threadIdx.x;
        float m = fmaxf(fmaxf(wmax[0][i], wmax[1][i]), fmaxf(wmax[2][i], wmax[3][i]));
        atomicMax(maxbuf + b * 8 + 3 + i, __float_as_uint(m));
    }
}

// select normalization reciprocal by quadrant
__device__ __forceinline__ float quad_inv(int gh, int gw,
                                          float inv_ad1, float inv_da1, float inv_dd1,
                                          float inv_a2, float inv_ad2, float inv_da2, float inv_dd2) {
    if (gh < 256) {
        if (gw < 256) {
            if (gh < 128) return (gw < 128) ? inv_a2 : inv_ad2;
            else          return (gw < 128) ? inv_da2 : inv_dd2;
        }
        return inv_ad1;
    }
    return (gw < 256) ? inv_da1 : inv_dd1;
}

// bilinear sample of g2 (a2*lfw) at output pixel (gh,gw), then * inv_a2 outside
__device__ __forceinline__ float bilin_g2(const float* __restrict__ g2b, int gh, int gw) {
    float sh = fminf(fmaxf(0.25f * (float)gh - 0.375f, 0.f), 127.f);
    float sw = fminf(fmaxf(0.25f * (float)gw - 0.375f, 0.f), 127.f);
    int r0 = (int)sh; float fr = sh - (float)r0; int r1 = min(r0 + 1, 127);
    int c0 = (int)sw; float fc = sw - (float)c0; int c1 = min(c0 + 1, 127);
    float g00 = g2b[r0 * 128 + c0];
    float g01 = g2b[r0 * 128 + c1];
    float g10 = g2b[r1 * 128 + c0];
    float g11 = g2b[r1 * 128 + c1];
    float t0 = g00 * (1.f - fr) + g10 * fr;
    float t1 = g01 * (1.f - fr) + g11 * fr;
    return t0 * (1.f - fc) + t1 * fc;
}

// Fused conv stage, 2-tile pipelined. Each 256-thread block does two stacked 128x8 tiles.
// Stage t0 -> sync -> prefetch t1's arr reads to regs -> compute+store t0 ->
// finish t1 staging (hot g2 bilinear + LDS writes) -> sync -> compute+store t1.
__global__ __launch_bounds__(256) void k_conv(const float* __restrict__ arr_hf,
                                              const float* __restrict__ g2,
                                              const unsigned int* __restrict__ maxbuf,
                                              const float* __restrict__ cw,
                                              const float* __restrict__ cb,
                                              float* __restrict__ out) {
    int b   = blockIdx.z;
    int th0 = blockIdx.y * 16;           // tile0: rows th0..th0+7, tile1: +8
    int tw0 = blockIdx.x * 128;
    int tid = threadIdx.x;

    __shared__ __align__(16) float tile[2][2][10][132];   // [buf][ch][row][col]

    const unsigned int* mb = maxbuf + b * 8;
    float inv_ad1 = 1.f / __uint_as_float(mb[0]);
    float inv_da1 = 1.f / __uint_as_float(mb[1]);
    float inv_dd1 = 1.f / __uint_as_float(mb[2]);
    float inv_a2  = 1.f / __uint_as_float(mb[3]);
    float inv_ad2 = 1.f / __uint_as_float(mb[4]);
    float inv_da2 = 1.f / __uint_as_float(mb[5]);
    float inv_dd2 = 1.f / __uint_as_float(mb[6]);

    const float* arr = arr_hf + (size_t)b * (512 * 512);
    const float* g2b = g2 + b * 16384;

    int wq  = tid & 31;   // w-quad: w0 = 4*wq
    int row = tid >> 5;   // output row within tile: 0..7
    size_t plane = 512 * 512;

    // ---- stage tile0 (full) ----
    for (int i = tid; i < 10 * 130; i += 256) {
        int r_ = i / 130;
        int col = i - r_ * 130;
        int gh = th0 + r_ - 1;
        int gw = tw0 + col - 1;
        float v0 = 0.f, v1 = 0.f;
        if (gh >= 0 && gh < 512 && gw >= 0 && gw < 512) {
            v0 = arr[gh * 512 + gw] * quad_inv(gh, gw, inv_ad1, inv_da1, inv_dd1, inv_a2, inv_ad2, inv_da2, inv_dd2);
            v1 = bilin_g2(g2b, gh, gw) * inv_a2;
        }
        tile[0][0][r_][col] = v0;
        tile[0][1][r_][col] = v1;
    }
    __syncthreads();

    // ---- prefetch tile1's arr values into registers (HBM latency hides under tile0 FMA) ----
    float pre[6];
    #pragma unroll
    for (int it = 0; it < 6; ++it) {
        int i = tid + it * 256;
        float pv = 0.f;
        if (i < 1300) {
            int r_ = i / 130;
            int col = i - r_ * 130;
            int gh = th0 + 8 + r_ - 1;
            int gw = tw0 + col - 1;
            if (gh >= 0 && gh < 512 && gw >= 0 && gw < 512) pv = arr[gh * 512 + gw];
        }
        pre[it] = pv;
    }

    // ---- compute + store tile0 ----
    {
        float acc[16][4];
        #pragma unroll
        for (int oc = 0; oc < 16; ++oc) {
            float bvv = cb[oc];
            #pragma unroll
            for (int j = 0; j < 4; ++j) acc[oc][j] = bvv;
        }
        #pragma unroll
        for (int ic = 0; ic < 2; ++ic)
            #pragma unroll
            for (int kh = 0; kh < 3; ++kh) {
                const float* rp_ = &tile[0][ic][row + kh][4 * wq];
                float v[6];
                { float4 t = *(const float4*)rp_; v[0] = t.x; v[1] = t.y; v[2] = t.z; v[3] = t.w;
                  float2 s = *(const float2*)(rp_ + 4); v[4] = s.x; v[5] = s.y; }
                #pragma unroll
                for (int kw = 0; kw < 3; ++kw)
                    #pragma unroll
                    for (int oc = 0; oc < 16; ++oc) {
                        float wv = cw[oc * 18 + ic * 9 + kh * 3 + kw];
                        #pragma unroll
                        for (int j = 0; j < 4; ++j)
                            acc[oc][j] = fmaf(v[j + kw], wv, acc[oc][j]);
                    }
            }
        float* ob = out + (size_t)(b * 16) * plane + (size_t)(th0 + row) * 512 + tw0 + 4 * wq;
        #pragma unroll
        for (int oc = 0; oc < 16; ++oc) {
            float4 val = make_float4(acc[oc][0], acc[oc][1], acc[oc][2], acc[oc][3]);
            *(float4*)(ob + (size_t)oc * plane) = val;
        }
    }

    // ---- finish staging tile1 (bilinear from hot g2; arr values from regs) ----
    #pragma unroll
    for (int it = 0; it < 6; ++it) {
        int i = tid + it * 256;
        if (i < 1300) {
            int r_ = i / 130;
            int col = i - r_ * 130;
            int gh = th0 + 8 + r_ - 1;
            int gw = tw0 + col - 1;
            float v0 = 0.f, v1 = 0.f;
            if (gh >= 0 && gh < 512 && gw >= 0 && gw < 512) {
                v0 = pre[it] * quad_inv(gh, gw, inv_ad1, inv_da1, inv_dd1, inv_a2, inv_ad2, inv_da2, inv_dd2);
                v1 = bilin_g2(g2b, gh, gw) * inv_a2;
            }
            tile[1][0][r_][col] = v0;
            tile[1][1][r_][col] = v1;
        }
    }
    __syncthreads();

    // ---- compute + store tile1 ----
    {
        float acc[16][4];
        #pragma unroll
        for (int oc = 0; oc < 16; ++oc) {
            float bvv = cb[oc];
            #pragma unroll
            for (int j = 0; j < 4; ++j) acc[oc][j] = bvv;
        }
        #pragma unroll
        for (int ic = 0; ic < 2; ++ic)
            #pragma unroll
            for (int kh = 0; kh < 3; ++kh) {
                const float* rp_ = &tile[1][ic][row + kh][4 * wq];
                float v[6];
                { float4 t = *(const float4*)rp_; v[0] = t.x; v[1] = t.y; v[2] = t.z; v[3] = t.w;
                  float2 s = *(const float2*)(rp_ + 4); v[4] = s.x; v[5] = s.y; }
                #pragma unroll
                for (int kw = 0; kw < 3; ++kw)
                    #pragma unroll
                    for (int oc = 0; oc < 16; ++oc) {
                        float wv = cw[oc * 18 + ic * 9 + kh * 3 + kw];
                        #pragma unroll
                        for (int j = 0; j < 4; ++j)
                            acc[oc][j] = fmaf(v[j + kw], wv, acc[oc][j]);
                    }
            }
        float* ob = out + (size_t)(b * 16) * plane + (size_t)(th0 + 8 + row) * 512 + tw0 + 4 * wq;
        #pragma unroll
        for (int oc = 0; oc < 16; ++oc) {
            float4 val = make_float4(acc[oc][0], acc[oc][1], acc[oc][2], acc[oc][3]);
            *(float4*)(ob + (size_t)oc * plane) = val;
        }
    }
}

extern "C" void kernel_launch(void* const* d_in, const int* in_sizes, int n_in,
                              void* d_out, int out_size, void* d_ws, size_t ws_size,
                              hipStream_t stream) {
    const float* x   = (const float*)d_in[0];
    const float* hfw = (const float*)d_in[1];
    const float* lfw = (const float*)d_in[2];
    const float* cw  = (const float*)d_in[3];
    const float* cb  = (const float*)d_in[4];
    float* out = (float*)d_out;

    char* ws = (char*)d_ws;
    float* arr_hf       = (float*)(ws);                    // 16 MiB: 16 x 512 x 512 (pre-multiplied by hfw)
    float* a1           = (float*)(ws + 16777216);         //  4 MiB: 16 x 256 x 256
    float* g2           = (float*)(ws + 20971520);         //  1 MiB: 16 x 128 x 128 (a2 * lfw)
    unsigned int* maxbf = (unsigned int*)(ws + 22020096);  //  16 x 8 u32

    (void)hipMemsetAsync(maxbf, 0, NB * 8 * sizeof(unsigned int), stream);
    k_dwt1<<<dim3(256, NB), 256, 0, stream>>>(x, hfw, arr_hf, a1, maxbf);
    k_dwt2<<<dim3(64, NB), 256, 0, stream>>>(a1, hfw, lfw, arr_hf, g2, maxbf);
    k_conv<<<dim3(4, 32, NB), 256, 0, stream>>>(arr_hf, g2, maxbf, cw, cb, out);
}